// Round 3
// baseline (78.769 us; speedup 1.0000x reference)
//
#include <hip/hip_runtime.h>
#include <math.h>

#define NC 32
#define NSTEPS 32

constexpr int BLOCK = 256;
constexpr int PTS = 4;                 // 4 chains/thread; 32 waves/CU TLP
constexpr int CHUNK = BLOCK * PTS;     // 1024 points per block

// DUAL-PIPE gather experiment (this round):
//   The kernel is DS-issue-bound: 4096 8B/lane gathers per CU at ~16 cyc
//   each (~28 us). Bank-conflict fix (round 2) was neutral -> cost is
//   per-instruction, not conflicts. Fix: split the 4 chains/thread across
//   TWO independent per-CU pipes:
//     chains 0,1 -> LDS table (ds_read2_b32, split A/B layout)
//     chains 2,3 -> global table in a block-private d_ws slice (256 B,
//                   L1-resident after first touch; global_load_dwordx2
//                   on the TA/TCP pipe, concurrent with DS)
//   Table values are computed once by wave 0 and stored to BOTH copies ->
//   bitwise-identical math per chain -> absmax unchanged (0.15625).
//
// Per-step body per chain stays 4 VALU + 1 load:
//   z = 32*x (2^5 scale, exact); c = (int)med3(z, 0, 31.5)
//   z' = fmaf(A, z, 32*b*phi)
__global__ void __launch_bounds__(BLOCK)
cpab_kernel(const float* __restrict__ points,
            const float* __restrict__ theta,
            const float* __restrict__ basis,
            float* __restrict__ out,
            float2* __restrict__ wstab,
            int n_points, int d) {
    __shared__ float tab[2 * NC];      // [0..31]=A, [32..63]=32*b*phi

    const int blocks_per_theta = n_points / CHUNK;   // 256
    const int j = blockIdx.x / blocks_per_theta;
    const int tid = threadIdx.x;

    // block-private global table slice (2048 blocks * 256 B = 512 KB of ws)
    float2* __restrict__ gt = wstab + blockIdx.x * NC;

    if (tid < NC) {
        const int c = tid;
        const float* __restrict__ th = theta + j * d;
        const float* __restrict__ ba = basis + (2 * c) * d;
        const float* __restrict__ bb = basis + (2 * c + 1) * d;
        float a = 0.0f, b = 0.0f;
#pragma unroll 6
        for (int k = 0; k < d; ++k) {
            float t = th[k];
            a = fmaf(ba[k], t, a);
            b = fmaf(bb[k], t, b);
        }
        const float dT = 1.0f / (float)NSTEPS;
        a *= dT;
        b *= dT;
        float A = expf(a);
        // phi(a) = (e^a - 1)/a, stable small-a branch (matches reference)
        float phi = (fabsf(a) < 1e-6f) ? (1.0f + 0.5f * a) : (expm1f(a) / a);
        float Bs = 32.0f * (b * phi);  // exact 2^5 scale of B
        tab[c]      = A;
        tab[c + NC] = Bs;
        gt[c] = make_float2(A, Bs);    // identical values -> identical math
    }
    __syncthreads();   // drains vmcnt -> gt stores visible block-wide

    const int base = (blockIdx.x % blocks_per_theta) * CHUNK + tid * PTS;

    float z[PTS];
    {
        float4 v = *(const float4*)(points + base);
        z[0] = v.x * 32.0f; z[1] = v.y * 32.0f;    // exact 2^5 scale
        z[2] = v.z * 32.0f; z[3] = v.w * 32.0f;
    }

#pragma unroll
    for (int s = 0; s < NSTEPS; ++s) {
#pragma unroll
        for (int i = 0; i < PTS; ++i) {
            float zc = fminf(fmaxf(z[i], 0.0f), 31.5f);  // v_med3_f32
            int c = (int)zc;                             // v_cvt_i32_f32
            float A, B;
            if (i < 2) {                 // DS pipe: one ds_read2_b32
                A = tab[c];
                B = tab[c + NC];
            } else {                     // VMEM pipe: global_load_dwordx2 (L1)
                float2 t = gt[c];
                A = t.x;
                B = t.y;
            }
            z[i] = fmaf(A, z[i], B);                     // v_fma_f32
        }
    }

    const float inv = 1.0f / 32.0f;                  // exact scale back
    float4 o = make_float4(z[0] * inv, z[1] * inv, z[2] * inv, z[3] * inv);
    *(float4*)(out + j * n_points + base) = o;
}

extern "C" void kernel_launch(void* const* d_in, const int* in_sizes, int n_in,
                              void* d_out, int out_size, void* d_ws, size_t ws_size,
                              hipStream_t stream) {
    const float* points = (const float*)d_in[0];  // [1, n_points]
    const float* theta  = (const float*)d_in[1];  // [n_theta, d]
    const float* basis  = (const float*)d_in[2];  // [2*NC, d]

    int n_points = in_sizes[0];
    int d        = in_sizes[2] / (2 * NC);        // 30
    int n_theta  = in_sizes[1] / d;               // 8

    int grid = n_theta * (n_points / CHUNK);      // 8 * 256 = 2048 blocks
    cpab_kernel<<<grid, BLOCK, 0, stream>>>(points, theta, basis,
                                            (float*)d_out, (float2*)d_ws,
                                            n_points, d);
}

// Round 5
// 71.794 us; speedup vs baseline: 1.0972x; 1.0972x over previous
//
#include <hip/hip_runtime.h>
#include <math.h>

#define NC 32
#define NSTEPS 32

constexpr int BLOCK = 256;
constexpr int PTS = 4;                 // 4 chains/thread; 32 waves/CU TLP
constexpr int CHUNK = BLOCK * PTS;     // 1024 points per block

// WAVE-SPECIALIZED DUAL-PIPE gather (this round):
//   Established: kernel is DS-gather-bound (~16 cyc per 8B/lane gather,
//   layout-independent: R0 float2 == R2 split A/B). Numerics margin is
//   ~17% (0.15625 vs threshold 0.1825) -> NO precision trades; every
//   chain must execute the bitwise-identical fma sequence.
//   R3 (per-chain DS/VMEM mix inside each wave) regressed +9us because the
//   dependent vmcnt wait each step also serialized that wave's DS chains.
//   Fix: specialize per WAVE. Waves 0-2: LDS table (ds_read2_b32).
//   Wave 3: block-private global table (L1-resident 256 B,
//   global_load_dwordx2 on the TA/TCP pipe, concurrent with DS waves).
//   Both tables hold bitwise-identical values (R3 proved the gt path
//   reproduces absmax 0.15625 exactly).
//
// Per-step body per chain (both pipes): 4 VALU + 1 load:
//   z = 32*x (2^5 scale, exact); c = (int)med3(z, 0, 31.5)
//   z' = fmaf(A, z, 32*b*phi)
__global__ void __launch_bounds__(BLOCK)
cpab_kernel(const float* __restrict__ points,
            const float* __restrict__ theta,
            const float* __restrict__ basis,
            float* __restrict__ out,
            float2* __restrict__ wstab,
            int n_points, int d) {
    __shared__ float tab[2 * NC];      // [0..31]=A, [32..63]=32*b*phi

    const int blocks_per_theta = n_points / CHUNK;   // 256
    const int j = blockIdx.x / blocks_per_theta;
    const int tid = threadIdx.x;

    // block-private global table slice (2048 blocks * 256 B = 512 KB of ws)
    float2* __restrict__ gt = wstab + blockIdx.x * NC;

    if (tid < NC) {
        const int c = tid;
        const float* __restrict__ th = theta + j * d;
        const float* __restrict__ ba = basis + (2 * c) * d;
        const float* __restrict__ bb = basis + (2 * c + 1) * d;
        float a = 0.0f, b = 0.0f;
#pragma unroll 6
        for (int k = 0; k < d; ++k) {
            float t = th[k];
            a = fmaf(ba[k], t, a);
            b = fmaf(bb[k], t, b);
        }
        const float dT = 1.0f / (float)NSTEPS;
        a *= dT;
        b *= dT;
        float A = expf(a);
        // phi(a) = (e^a - 1)/a, stable small-a branch (matches reference)
        float phi = (fabsf(a) < 1e-6f) ? (1.0f + 0.5f * a) : (expm1f(a) / a);
        float Bs = 32.0f * (b * phi);  // exact 2^5 scale of B
        tab[c]      = A;
        tab[c + NC] = Bs;
        gt[c] = make_float2(A, Bs);    // bitwise-identical values
    }
    __syncthreads();   // writer drains vmcnt before s_barrier -> gt visible

    const int base = (blockIdx.x % blocks_per_theta) * CHUNK + tid * PTS;

    float z[PTS];
    {
        float4 v = *(const float4*)(points + base);
        z[0] = v.x * 32.0f; z[1] = v.y * 32.0f;    // exact 2^5 scale
        z[2] = v.z * 32.0f; z[3] = v.w * 32.0f;
    }

    if (tid < 192) {
        // ---- DS waves 0..2: one ds_read2_b32 per chain-step ----
#pragma unroll
        for (int s = 0; s < NSTEPS; ++s) {
#pragma unroll
            for (int i = 0; i < PTS; ++i) {
                float zc = fminf(fmaxf(z[i], 0.0f), 31.5f);  // v_med3_f32
                int c = (int)zc;                             // v_cvt_i32_f32
                float A = tab[c];                            // \ ds_read2_b32
                float B = tab[c + NC];                       // /  offset1:32
                z[i] = fmaf(A, z[i], B);                     // v_fma_f32
            }
        }
    } else {
        // ---- VMEM wave 3: one global_load_dwordx2 per chain-step (L1) ----
#pragma unroll
        for (int s = 0; s < NSTEPS; ++s) {
#pragma unroll
            for (int i = 0; i < PTS; ++i) {
                float zc = fminf(fmaxf(z[i], 0.0f), 31.5f);
                int c = (int)zc;
                float2 t = gt[c];                            // VMEM pipe
                z[i] = fmaf(t.x, z[i], t.y);
            }
        }
    }

    const float inv = 1.0f / 32.0f;                  // exact scale back
    float4 o = make_float4(z[0] * inv, z[1] * inv, z[2] * inv, z[3] * inv);
    *(float4*)(out + j * n_points + base) = o;
}

extern "C" void kernel_launch(void* const* d_in, const int* in_sizes, int n_in,
                              void* d_out, int out_size, void* d_ws, size_t ws_size,
                              hipStream_t stream) {
    const float* points = (const float*)d_in[0];  // [1, n_points]
    const float* theta  = (const float*)d_in[1];  // [n_theta, d]
    const float* basis  = (const float*)d_in[2];  // [2*NC, d]

    int n_points = in_sizes[0];
    int d        = in_sizes[2] / (2 * NC);        // 30
    int n_theta  = in_sizes[1] / d;               // 8

    int grid = n_theta * (n_points / CHUNK);      // 8 * 256 = 2048 blocks
    cpab_kernel<<<grid, BLOCK, 0, stream>>>(points, theta, basis,
                                            (float*)d_out, (float2*)d_ws,
                                            n_points, d);
}

// Round 7
// 69.541 us; speedup vs baseline: 1.1327x; 1.0324x over previous
//
#include <hip/hip_runtime.h>
#include <math.h>

#define NC 32
#define NSTEPS 32

constexpr int BLOCK = 256;
constexpr int PTS = 4;                 // 4 chains/thread; 32 waves/CU TLP
constexpr int CHUNK = BLOCK * PTS;     // 1024 points per block

// SESSION-BEST KERNEL (R0's 69.087 us version).
//
// Established by rounds 0-5 (all measured on MI355X):
//   - Kernel is DS-gather-throughput-bound: 4096 8B/lane gathers per CU
//     at ~16 cyc each (~27 us), layout-INDEPENDENT:
//       R0 float2 tab[32] (ds_read_b64)          = 69.1 us
//       R2 split A/B tab[64], conflict-free      = 69.9 us (neutral)
//   - VMEM cannot co-serve the gather:
//       R3 per-chain DS/VMEM mix   +9.0 us (vmcnt stalls serialize wave)
//       R5 wave-specialized split  +1.9 us (VMEM wave is the straggler)
//   - Payload halving (f16 table) numerically forbidden:
//       R4 absmax 0.699 > threshold 0.1825 (cell-boundary flips; the
//       exact kernel sits at 0.15625 -- only 17% margin -> NO precision
//       trades, every chain must run this exact fma sequence).
//   - Remaining total (~70 us) = harness ws-fill ~40.6 us (82% HBM peak,
//     unremovable) + out-clear ~1.3 us + kernel ~27 us (DS floor).
//
// Per-step body: 4 VALU + 1 DS:
//   state z = 256*x (2^8 scale: exact in fp32, commutes with RN rounding)
//   cell byte-address = (int)med3(z, 0, 255.5) & ~7
//     - med3 clamps (fminf(fmaxf)) -> v_med3_f32
//     - (int) = v_cvt_i32_f32 (trunc == floor for z>=0)
//     - & ~7 turns trunc(z) into 8*floor(z/8) = byte offset of float2 tab[cell]
//     - clamp bound 255.5: z in (255.5,256) still maps to cell 31 (correct),
//       z >= 256 clamps to cell 31, z < 0 clamps to cell 0 (matches jnp.clip)
//   z' = fmaf(A, z, 256*b*phi)  == 256 * fmaf(A, x, b*phi) bitwise
// Table (A, 256*B) in LDS; random gathers merge same-address lanes
// (<=2 distinct dword addrs per bank -> free 2-way case).
__global__ void __launch_bounds__(BLOCK)
cpab_kernel(const float* __restrict__ points,
            const float* __restrict__ theta,
            const float* __restrict__ basis,
            float* __restrict__ out,
            int n_points, int d) {
    __shared__ float2 tab[NC];         // (A, 256*B)

    const int blocks_per_theta = n_points / CHUNK;   // 256
    const int j = blockIdx.x / blocks_per_theta;
    const int tid = threadIdx.x;

    if (tid < NC) {
        const int c = tid;
        const float* __restrict__ th = theta + j * d;
        const float* __restrict__ ba = basis + (2 * c) * d;
        const float* __restrict__ bb = basis + (2 * c + 1) * d;
        float a = 0.0f, b = 0.0f;
#pragma unroll 6
        for (int k = 0; k < d; ++k) {
            float t = th[k];
            a = fmaf(ba[k], t, a);
            b = fmaf(bb[k], t, b);
        }
        const float dT = 1.0f / (float)NSTEPS;
        a *= dT;
        b *= dT;
        float A = expf(a);
        // phi(a) = (e^a - 1)/a, stable small-a branch (matches reference)
        float phi = (fabsf(a) < 1e-6f) ? (1.0f + 0.5f * a) : (expm1f(a) / a);
        tab[c] = make_float2(A, 256.0f * (b * phi));  // exact 2^8 scale of B
    }
    __syncthreads();

    const int base = (blockIdx.x % blocks_per_theta) * CHUNK + tid * PTS;

    float z[PTS];
    {
        float4 v = *(const float4*)(points + base);
        z[0] = v.x * 256.0f; z[1] = v.y * 256.0f;    // exact 2^8 scale
        z[2] = v.z * 256.0f; z[3] = v.w * 256.0f;
    }

    const char* tb = (const char*)tab;
#pragma unroll
    for (int s = 0; s < NSTEPS; ++s) {
#pragma unroll
        for (int i = 0; i < PTS; ++i) {
            float zc = fminf(fmaxf(z[i], 0.0f), 255.5f);  // v_med3_f32
            int addr = ((int)zc) & ~7;                    // v_cvt + v_and
            float2 t = *(const float2*)(tb + addr);       // ds_read_b64
            z[i] = fmaf(t.x, z[i], t.y);                  // v_fma_f32
        }
    }

    const float inv = 1.0f / 256.0f;                 // exact scale back
    float4 o = make_float4(z[0] * inv, z[1] * inv, z[2] * inv, z[3] * inv);
    *(float4*)(out + j * n_points + base) = o;
}

extern "C" void kernel_launch(void* const* d_in, const int* in_sizes, int n_in,
                              void* d_out, int out_size, void* d_ws, size_t ws_size,
                              hipStream_t stream) {
    const float* points = (const float*)d_in[0];  // [1, n_points]
    const float* theta  = (const float*)d_in[1];  // [n_theta, d]
    const float* basis  = (const float*)d_in[2];  // [2*NC, d]

    int n_points = in_sizes[0];
    int d        = in_sizes[2] / (2 * NC);        // 30
    int n_theta  = in_sizes[1] / d;               // 8

    int grid = n_theta * (n_points / CHUNK);      // 8 * 256 = 2048 blocks
    cpab_kernel<<<grid, BLOCK, 0, stream>>>(points, theta, basis,
                                            (float*)d_out, n_points, d);
}